// Round 4
// baseline (225.323 us; speedup 1.0000x reference)
//
#include <hip/hip_runtime.h>
#include <hip/hip_bf16.h>

// CausalSelfAttention, MI355X. B=4,T=2048,C=768,H=12,HS=64.
// cvt/transpose -> GEMM(qkv,+bias,q pre-scaled 0.125*log2e) ->
// flash-attn (swapped QK^T, exp2 no-max, packed P/V LDS) -> GEMM(proj,+bias).

typedef short s16x8 __attribute__((ext_vector_type(8)));
typedef float f32x4 __attribute__((ext_vector_type(4)));
typedef unsigned short u16x4 __attribute__((ext_vector_type(4)));
typedef unsigned short u16x8 __attribute__((ext_vector_type(8)));

#define MFMA16 __builtin_amdgcn_mfma_f32_16x16x32_bf16

__device__ __forceinline__ unsigned short f2bf(float f) {
    __hip_bfloat16 h = __float2bfloat16(f);   // RN; compiler emits HW cvt (m240)
    return *reinterpret_cast<unsigned short*>(&h);
}

__device__ __forceinline__ void gload16(const unsigned short* g, unsigned short* l) {
    __builtin_amdgcn_global_load_lds(
        (__attribute__((address_space(1))) void*)(const void*)g,
        (__attribute__((address_space(3))) void*)l, 16, 0, 0);
}

__global__ __launch_bounds__(256) void cvt_f32_bf16(
    const float* __restrict__ src, unsigned short* __restrict__ dst, int n4)
{
    int i = blockIdx.x * 256 + threadIdx.x;
    if (i >= n4) return;
    float4 v = reinterpret_cast<const float4*>(src)[i];
    u16x4 o = { f2bf(v.x), f2bf(v.y), f2bf(v.z), f2bf(v.w) };
    reinterpret_cast<u16x4*>(dst)[i] = o;
}

// src [R][C] f32 -> dst [C][R] bf16
__global__ __launch_bounds__(256) void cvt_transpose(
    const float* __restrict__ src, unsigned short* __restrict__ dst, int R, int C)
{
    __shared__ unsigned short tile[32][33];
    const int c0 = blockIdx.x * 32, r0 = blockIdx.y * 32;
    const int tx = threadIdx.x & 31, ty = threadIdx.x >> 5;
#pragma unroll
    for (int j = 0; j < 32; j += 8)
        tile[ty + j][tx] = f2bf(src[(size_t)(r0 + ty + j) * C + c0 + tx]);
    __syncthreads();
#pragma unroll
    for (int j = 0; j < 32; j += 8)
        dst[(size_t)(c0 + ty + j) * R + r0 + tx] = tile[tx][ty + j];
}

// C[M,N] = A[M,K] @ Bt[N,K]^T + bias. 128x128 tile, BK=64, XOR-swizzled LDS
// (T2: col_slot ^ row&7; global src pre-swizzled since gload_lds is linear).
template<bool SCALEQ, bool OUT_BF16>
__global__ __launch_bounds__(256, 2) void gemm_bt(
    const unsigned short* __restrict__ A, const unsigned short* __restrict__ Bt,
    const float* __restrict__ bias, void* __restrict__ Cout,
    int M, int N, int K)
{
    __shared__ unsigned short lds_a[128 * 64];
    __shared__ unsigned short lds_b[128 * 64];

    const int tid = threadIdx.x, lane = tid & 63, w = tid >> 6;
    const int wr = w >> 1, wc = w & 1;
    const int lr = lane & 15, lg = lane >> 4;

    // bijective XCD swizzle (nwg % 8 == 0 for both call sites)
    const int nbx = gridDim.x;
    const int bid = blockIdx.x + nbx * blockIdx.y;
    const int cpx = (nbx * gridDim.y) >> 3;
    const int swz = (bid & 7) * cpx + (bid >> 3);
    const int m0 = (swz / nbx) * 128, n0 = (swz % nbx) * 128;

    f32x4 acc[4][4];
#pragma unroll
    for (int mi = 0; mi < 4; ++mi)
#pragma unroll
        for (int ni = 0; ni < 4; ++ni)
            acc[mi][ni] = f32x4{0.f, 0.f, 0.f, 0.f};

    // staging: lane l -> row 8w+(l>>3), pre-swizzled col slot (l&7)^(l>>3)
    const int srow = 8 * w + (lane >> 3);
    const int sslot = ((lane & 7) ^ (lane >> 3)) * 8;
    const unsigned short* Ap = A  + (size_t)(m0 + srow) * K + sslot;
    const unsigned short* Bp = Bt + (size_t)(n0 + srow) * K + sslot;
    unsigned short* la = lds_a + w * 512;     // wave-uniform dest bases
    unsigned short* lb = lds_b + w * 512;

    for (int k0 = 0; k0 < K; k0 += 64) {
#pragma unroll
        for (int p = 0; p < 4; ++p) {
            gload16(Ap + (size_t)(32 * p) * K + k0, la + 2048 * p);
            gload16(Bp + (size_t)(32 * p) * K + k0, lb + 2048 * p);
        }
        __syncthreads();

#pragma unroll
        for (int kh = 0; kh < 2; ++kh) {
            s16x8 af[4], bfr[4];
#pragma unroll
            for (int mi = 0; mi < 4; ++mi) {
                const int row = wr * 64 + mi * 16 + lr;
                af[mi] = *reinterpret_cast<const s16x8*>(
                    &lds_a[row * 64 + ((kh * 32 + lg * 8) ^ ((row & 7) << 3))]);
            }
#pragma unroll
            for (int ni = 0; ni < 4; ++ni) {
                const int row = wc * 64 + ni * 16 + lr;
                bfr[ni] = *reinterpret_cast<const s16x8*>(
                    &lds_b[row * 64 + ((kh * 32 + lg * 8) ^ ((row & 7) << 3))]);
            }
#pragma unroll
            for (int mi = 0; mi < 4; ++mi)
#pragma unroll
                for (int ni = 0; ni < 4; ++ni)
                    acc[mi][ni] = MFMA16(af[mi], bfr[ni], acc[mi][ni], 0, 0, 0);
        }
        __syncthreads();
    }

#pragma unroll
    for (int ni = 0; ni < 4; ++ni) {
        int col = n0 + wc * 64 + ni * 16 + lr;
        float bs = bias[col];
        float scq = (SCALEQ && col < 768) ? 0.18033688011112042f : 1.0f; // 0.125*log2(e)
#pragma unroll
        for (int mi = 0; mi < 4; ++mi)
#pragma unroll
            for (int r = 0; r < 4; ++r) {
                int row = m0 + wr * 64 + mi * 16 + lg * 4 + r;
                float v = (acc[mi][ni][r] + bs) * scq;
                if (OUT_BF16)
                    ((unsigned short*)Cout)[(size_t)row * N + col] = f2bf(v);
                else
                    ((float*)Cout)[(size_t)row * N + col] = v;
            }
    }
}

// Flash attention, causal, exp2-domain, swapped QK^T (P keys lane-local).
// Grid (48,16), qt=15-by (heavy first). QBLK=128 (wave: 32 rows), KVBLK=64.
__global__ __launch_bounds__(256, 4) void attn_fwd(
    const unsigned short* __restrict__ qkv, unsigned short* __restrict__ att)
{
    __shared__ unsigned short lds_k[64 * 72];      // K [key][d], stride-72
    __shared__ unsigned short lds_v[64 * 72];      // V^T [d][key ^ ((d>>3&7)<<3)]
    __shared__ unsigned short lds_p[4][32 * 72];   // per-wave P [q][key]

    const int tid = threadIdx.x, lane = tid & 63, w = tid >> 6;
    const int lr = lane & 15, lg = lane >> 4;
    const int bh = blockIdx.x;
    const int qt = 15 - blockIdx.y;
    const int b = bh / 12, h = bh % 12;
    const size_t bT = (size_t)b * 2048;
    const int wq = qt * 128 + w * 32;

    // Q fragments (B-operand now: col=q=lr, k=lg*8+i — same per-lane data)
    s16x8 qf[2][2];
#pragma unroll
    for (int mi = 0; mi < 2; ++mi) {
        const size_t qoff = (bT + wq + mi * 16 + lr) * 2304 + h * 64 + lg * 8;
        qf[mi][0] = *reinterpret_cast<const s16x8*>(qkv + qoff);
        qf[mi][1] = *reinterpret_cast<const s16x8*>(qkv + qoff + 32);
    }

    f32x4 o[2][4];
    f32x4 lsum[2];
#pragma unroll
    for (int mi = 0; mi < 2; ++mi) {
        lsum[mi] = f32x4{0.f, 0.f, 0.f, 0.f};
#pragma unroll
        for (int dt = 0; dt < 4; ++dt) o[mi][dt] = f32x4{0.f, 0.f, 0.f, 0.f};
    }

    // K staging: thread = key (tid>>2), 16 d at (tid&3)*16
    const int ksr = tid >> 2, ksc = (tid & 3) * 16;
    const unsigned short* kbase = qkv + (bT + ksr) * 2304 + 768 + h * 64 + ksc;
    unsigned short* kdst = &lds_k[ksr * 72 + ksc];
    // V staging: thread = key-pair (tid>>3), 8 d at (tid&7)*8
    const int vkp = tid >> 3, vdb = (tid & 7) * 8;
    const unsigned short* vbase = qkv + (bT + 2 * vkp) * 2304 + 1536 + h * 64 + vdb;

    const int nkt = 2 * (qt + 1);

    // prologue: prefetch tile 0
    u16x8 kr0 = *reinterpret_cast<const u16x8*>(kbase);
    u16x8 kr1 = *reinterpret_cast<const u16x8*>(kbase + 8);
    u16x8 vr0 = *reinterpret_cast<const u16x8*>(vbase);
    u16x8 vr1 = *reinterpret_cast<const u16x8*>(vbase + 2304);

    for (int kt = 0; kt < nkt; ++kt) {
        const int kv0 = kt * 64;
        // --- regs -> LDS ---
        *reinterpret_cast<u16x8*>(kdst)     = kr0;
        *reinterpret_cast<u16x8*>(kdst + 8) = kr1;
#pragma unroll
        for (int j = 0; j < 8; ++j) {
            const int d = vdb + j;
            unsigned pk = (unsigned)vr0[j] | ((unsigned)vr1[j] << 16);
            *reinterpret_cast<unsigned*>(
                &lds_v[d * 72 + ((2 * vkp) ^ (((d >> 3) & 7) << 3))]) = pk;
        }
        __syncthreads();

        // --- prefetch tile kt+1 (overlaps compute) ---
        {
            const int ktn = (kt + 1 < nkt) ? kt + 1 : kt;
            const size_t off = (size_t)(ktn * 64) * 2304;
            kr0 = *reinterpret_cast<const u16x8*>(kbase + off);
            kr1 = *reinterpret_cast<const u16x8*>(kbase + off + 8);
            vr0 = *reinterpret_cast<const u16x8*>(vbase + off);
            vr1 = *reinterpret_cast<const u16x8*>(vbase + off + 2304);
        }

        if (kv0 <= wq + 31) {     // wave-level causal skip
            // --- S^T = K Q^T: out row=key(4lg+r), col=q(lr) ---
            f32x4 sf[2][4];
#pragma unroll
            for (int mi = 0; mi < 2; ++mi)
#pragma unroll
                for (int n = 0; n < 4; ++n) sf[mi][n] = f32x4{0.f, 0.f, 0.f, 0.f};
            __builtin_amdgcn_s_setprio(1);
#pragma unroll
            for (int kk = 0; kk < 2; ++kk)
#pragma unroll
                for (int n = 0; n < 4; ++n) {
                    s16x8 kf = *reinterpret_cast<const s16x8*>(
                        &lds_k[(n * 16 + lr) * 72 + kk * 32 + lg * 8]);
                    sf[0][n] = MFMA16(kf, qf[0][kk], sf[0][n], 0, 0, 0);
                    sf[1][n] = MFMA16(kf, qf[1][kk], sf[1][n], 0, 0, 0);
                }
            __builtin_amdgcn_s_setprio(0);

            // --- causal mask (partial tiles only) ---
            if (kv0 + 63 > wq) {
#pragma unroll
                for (int mi = 0; mi < 2; ++mi)
#pragma unroll
                    for (int n = 0; n < 4; ++n)
#pragma unroll
                        for (int r = 0; r < 4; ++r) {
                            int key = kv0 + n * 16 + 4 * lg + r;
                            int qrow = wq + mi * 16 + lr;
                            if (key > qrow) sf[mi][n][r] = -1.0e30f;
                        }
            }

            // --- p = exp2(s); 4 consecutive keys -> one b64 P write ---
#pragma unroll
            for (int mi = 0; mi < 2; ++mi)
#pragma unroll
                for (int n = 0; n < 4; ++n) {
                    f32x4 p;
#pragma unroll
                    for (int r = 0; r < 4; ++r) p[r] = __builtin_amdgcn_exp2f(sf[mi][n][r]);
                    lsum[mi] += p;
                    u16x4 pk = { f2bf(p[0]), f2bf(p[1]), f2bf(p[2]), f2bf(p[3]) };
                    *reinterpret_cast<u16x4*>(
                        &lds_p[w][(mi * 16 + lr) * 72 + n * 16 + 4 * lg]) = pk;
                }
            // per-wave buffer: compiler lgkmcnt ordering suffices

            // --- O += P V ---
            __builtin_amdgcn_s_setprio(1);
#pragma unroll
            for (int kk = 0; kk < 2; ++kk) {
                s16x8 pf0 = *reinterpret_cast<const s16x8*>(
                    &lds_p[w][lr * 72 + kk * 32 + lg * 8]);
                s16x8 pf1 = *reinterpret_cast<const s16x8*>(
                    &lds_p[w][(16 + lr) * 72 + kk * 32 + lg * 8]);
#pragma unroll
                for (int dt = 0; dt < 4; ++dt) {
                    const int vrow = dt * 16 + lr;
                    s16x8 vf = *reinterpret_cast<const s16x8*>(
                        &lds_v[vrow * 72 + ((kk * 32 + lg * 8) ^ (((vrow >> 3) & 7) << 3))]);
                    o[0][dt] = MFMA16(pf0, vf, o[0][dt], 0, 0, 0);
                    o[1][dt] = MFMA16(pf1, vf, o[1][dt], 0, 0, 0);
                }
            }
            __builtin_amdgcn_s_setprio(0);
        }
        __syncthreads();
    }

    // --- epilogue: row-sums are lane-local per q-row lr; reduce across lg ---
    float inv[2];
#pragma unroll
    for (int mi = 0; mi < 2; ++mi) {
        float s = lsum[mi][0] + lsum[mi][1] + lsum[mi][2] + lsum[mi][3];
        s += __shfl_xor(s, 16);
        s += __shfl_xor(s, 32);
        inv[mi] = 1.0f / s;           // lane L holds q-row (L&15) of half mi
    }

#pragma unroll
    for (int mi = 0; mi < 2; ++mi)
#pragma unroll
        for (int dt = 0; dt < 4; ++dt)
#pragma unroll
            for (int r = 0; r < 4; ++r) {
                int qrow = wq + mi * 16 + 4 * lg + r;
                float sc = __shfl(inv[mi], 4 * lg + r);
                att[(bT + qrow) * 768 + h * 64 + dt * 16 + lr] = f2bf(o[mi][dt][r] * sc);
            }
}

extern "C" void kernel_launch(void* const* d_in, const int* in_sizes, int n_in,
                              void* d_out, int out_size, void* d_ws, size_t ws_size,
                              hipStream_t stream) {
    const float* x      = (const float*)d_in[0];
    const float* W_attn = (const float*)d_in[1];
    const float* b_attn = (const float*)d_in[2];
    const float* W_proj = (const float*)d_in[3];
    const float* b_proj = (const float*)d_in[4];

    unsigned short* ws    = (unsigned short*)d_ws;
    unsigned short* x_bf  = ws;                       // 8192*768
    unsigned short* wa_t  = x_bf + 6291456;           // 2304*768 (transposed)
    unsigned short* wp_t  = wa_t + 1769472;           // 768*768  (transposed)
    unsigned short* qkv   = wp_t + 589824;            // 8192*2304
    unsigned short* att   = qkv + 18874368;           // 8192*768

    cvt_f32_bf16<<<6144, 256, 0, stream>>>(x, x_bf, 6291456 / 4);
    cvt_transpose<<<dim3(72, 24), 256, 0, stream>>>(W_attn, wa_t, 768, 2304);
    cvt_transpose<<<dim3(24, 24), 256, 0, stream>>>(W_proj, wp_t, 768, 768);

    gemm_bt<true , true ><<<dim3(18, 64), 256, 0, stream>>>(x_bf, wa_t, b_attn, qkv, 8192, 2304, 768);
    attn_fwd<<<dim3(48, 16), 256, 0, stream>>>(qkv, att);
    gemm_bt<false, false><<<dim3(6, 64), 256, 0, stream>>>(att, wp_t, b_proj, d_out, 8192, 768, 768);
}